// Round 1
// 446.818 us; speedup vs baseline: 1.0099x; 1.0099x over previous
//
#include <hip/hip_runtime.h>
#include <hip/hip_bf16.h>

#define EPS 1e-6f

constexpr int D  = 160;     // "D" axis (T//S)
constexpr int NN = 82944;   // C*H*W
constexpr int B  = 4;       // batches

typedef __bf16 bf16x8 __attribute__((ext_vector_type(8)));
typedef __bf16 bf16x4 __attribute__((ext_vector_type(4)));
typedef float  floatx4 __attribute__((ext_vector_type(4)));

// ---------------- Kernel A: partial Gram P[blk] = X_slab X_slab^T (bf16 MFMA) ----
// Two-stage split-K: each block writes a PRIVATE 160x160 partial tile with plain
// nontemporal streaming stores (was: 16.6M device-scope atomicAdds = 66 MB of
// RMW write-through traffic that serialized the whole kernel at ~121 G atomics/s).
constexpr int BK = 64;            // columns per LDS slab
constexpr int BKP = BK + 8;       // 144B row stride -> worst 2-way LDS aliasing (free)
constexpr int SLABS = 8;          // slabs per block
constexpr int COLS_PER_BLOCK = BK * SLABS;          // 512
constexpr int GRAM_BLOCKS = NN / COLS_PER_BLOCK;    // 162 (x4 batches = 648 blocks)

__global__ __launch_bounds__(256, 2)
void gram_kernel(const float* __restrict__ x, float* __restrict__ P)
{
    __shared__ __align__(16) __bf16 xs[D * BKP];   // 23.04 KB

    const int tid = threadIdx.x;
    const int batch = blockIdx.y;
    const int w  = tid >> 6;        // wave 0..3
    const int l  = tid & 63;
    const int lr = l & 15;          // row/col within 16-tile
    const int lq = l >> 4;          // quad 0..3
    const int itile0 = (w & 1) * 5; // wave's 5 row-tiles
    const int jtile0 = (w >> 1) * 5;// wave's 5 col-tiles
    const int srow = tid >> 4;      // staging: 16 lanes x 4 cols -> 64 cols/row
    const int scol = (tid & 15) * 4;

    const float* xb = x + (size_t)batch * D * NN + (size_t)blockIdx.x * COLS_PER_BLOCK;
    const float* pbase = xb + (size_t)srow * NN + scol;

    floatx4 acc[5][5] = {};
    float4 pf[10];

    // prologue: prefetch slab 0 into registers
    #pragma unroll
    for (int p = 0; p < 10; ++p)
        pf[p] = *(const float4*)(pbase + (size_t)p * 16 * NN);

    for (int s = 0; s < SLABS; ++s) {
        __syncthreads();   // previous compute done reading LDS
        // store phase: convert prefetched fp32 -> bf16 LDS
        #pragma unroll
        for (int p = 0; p < 10; ++p) {
            bf16x4 h = { (__bf16)pf[p].x, (__bf16)pf[p].y, (__bf16)pf[p].z, (__bf16)pf[p].w };
            *(bf16x4*)&xs[(srow + p * 16) * BKP + scol] = h;
        }
        __syncthreads();
        // issue next slab's loads NOW -- they fly during the MFMA phase below
        if (s + 1 < SLABS) {
            const float* pn = pbase + (s + 1) * BK;
            #pragma unroll
            for (int p = 0; p < 10; ++p)
                pf[p] = *(const float4*)(pn + (size_t)p * 16 * NN);
        }
        // compute phase: 2 k-chunks x 25 MFMA
        #pragma unroll
        for (int k = 0; k < BK / 32; ++k) {
            bf16x8 fa[5], fb[5];
            #pragma unroll
            for (int i = 0; i < 5; ++i) {
                fa[i] = *(const bf16x8*)&xs[((itile0 + i) * 16 + lr) * BKP + k * 32 + lq * 8];
                fb[i] = *(const bf16x8*)&xs[((jtile0 + i) * 16 + lr) * BKP + k * 32 + lq * 8];
            }
            #pragma unroll
            for (int i = 0; i < 5; ++i)
                #pragma unroll
                for (int j = 0; j < 5; ++j)
                    acc[i][j] = __builtin_amdgcn_mfma_f32_16x16x32_bf16(fa[i], fb[j], acc[i][j], 0, 0, 0);
        }
    }

    // epilogue: C/D layout col=lane&15, row=quad*4+reg (any global swap writes P^T == P)
    // Plain NT streaming stores to this block's PRIVATE partial tile -- no atomics.
    float* Pb = P + ((size_t)batch * GRAM_BLOCKS + blockIdx.x) * (size_t)(D * D);
    #pragma unroll
    for (int i = 0; i < 5; ++i) {
        const int d1base = (itile0 + i) * 16 + lq * 4;
        #pragma unroll
        for (int j = 0; j < 5; ++j) {
            const int d2 = (jtile0 + j) * 16 + lr;
            #pragma unroll
            for (int r = 0; r < 4; ++r)
                __builtin_nontemporal_store(acc[i][j][r], &Pb[(size_t)(d1base + r) * D + d2]);
        }
    }
}

// ---------------- Kernel A2: G[b] = sum_k P[b][k] (162-way split-K reduce) -------
// grid (25, 4): 256 threads x float4 = 1024 floats/block, 25 blocks cover 25600.
__global__ __launch_bounds__(256)
void reduce_kernel(const float* __restrict__ P, float* __restrict__ G)
{
    const int batch = blockIdx.y;
    const int i4 = (blockIdx.x * 256 + threadIdx.x) * 4;
    const float* p = P + (size_t)batch * GRAM_BLOCKS * D * D + i4;
    floatx4 s = {0.f, 0.f, 0.f, 0.f};
    #pragma unroll 9     // 162 = 9*18 -> 9 loads (144B) in flight per thread
    for (int k = 0; k < GRAM_BLOCKS; ++k)
        s += __builtin_nontemporal_load((const floatx4*)(p + (size_t)k * D * D));
    *(floatx4*)(G + (size_t)batch * D * D + i4) = s;
}

// ---------------- Kernel B: 4-step multiplicative update on G ----------------
__device__ __forceinline__ float block_reduce_bcast(float v, float* red)
{
    #pragma unroll
    for (int off = 32; off > 0; off >>= 1)
        v += __shfl_xor(v, off, 64);
    const int w = threadIdx.x >> 6;
    if ((threadIdx.x & 63) == 0) red[w] = v;
    __syncthreads();
    float s = red[0] + red[1] + red[2] + red[3];
    __syncthreads();
    return s;
}

__global__ __launch_bounds__(256)
void iter_kernel(const float* __restrict__ bases, const float* __restrict__ G,
                 float* __restrict__ bvec, float* __restrict__ svec)
{
    __shared__ float bs[D];
    __shared__ float red[4];
    const int batch = blockIdx.x;
    const int tid = threadIdx.x;
    const float* Gb = G + (size_t)batch * D * D;

    if (tid < D) bs[tid] = bases[batch * D + tid];
    __syncthreads();

    for (int step = 0; step < 4; ++step) {
        float v = (tid < D) ? bs[tid] * bs[tid] : 0.0f;
        const float btb = block_reduce_bcast(v, red);
        const float gamma = btb + EPS;           // exact at step 0 (coef==1); ~1e-6 rel after

        float m = 0.0f;
        if (tid < D) {
            const float* row = Gb + (size_t)tid * D;
            #pragma unroll 8
            for (int j = 0; j < D; j += 4) {
                float4 g4 = *(const float4*)(row + j);
                m += g4.x * bs[j] + g4.y * bs[j + 1] + g4.z * bs[j + 2] + g4.w * bs[j + 3];
            }
        }
        float bm = (tid < D) ? bs[tid] * m : 0.0f;
        const float beta = block_reduce_bcast(bm, red);   // b^T G b
        const float ctc = beta / (gamma * gamma);

        __syncthreads();
        if (tid < D) {
            const float bd = bs[tid];
            bs[tid] = bd * (m / gamma) / (bd * ctc + EPS);  // exact EPS in bases update
        }
        __syncthreads();
    }

    float v = (tid < D) ? bs[tid] * bs[tid] : 0.0f;
    const float btb = block_reduce_bcast(v, red);
    const float inv = 1.0f / (btb + EPS);
    if (tid < D) {
        bvec[batch * D + tid] = bs[tid];
        svec[batch * D + tid] = bs[tid] * inv;
    }
}

// ---------------- Kernel C: t = x^T b4 (fp32), out = (b4/btb4) t^T ----------------
// 256 cols/block: 40 independent loads in flight per thread.
__global__ __launch_bounds__(256)
void out_kernel(const float* __restrict__ x, const float* __restrict__ bvec,
                const float* __restrict__ svec, float* __restrict__ out)
{
    __shared__ float bsh[D], ssh[D];
    __shared__ floatx4 partA[256];
    __shared__ floatx4 partB[256];

    const int tid = threadIdx.x;
    const int batch = blockIdx.y;
    const int g = tid >> 5;          // d-group 0..7
    const int lane = tid & 31;
    const size_t base0 = (size_t)batch * D * NN + (size_t)blockIdx.x * 256 + lane * 4;
    const size_t base1 = base0 + 128;

    if (tid < D) { bsh[tid] = bvec[batch * D + tid]; ssh[tid] = svec[batch * D + tid]; }
    __syncthreads();

    floatx4 t0 = {0.f, 0.f, 0.f, 0.f};
    floatx4 t1 = {0.f, 0.f, 0.f, 0.f};
    #pragma unroll
    for (int d = g; d < D; d += 8) {
        floatx4 xv0 = *(const floatx4*)(x + base0 + (size_t)d * NN);
        floatx4 xv1 = *(const floatx4*)(x + base1 + (size_t)d * NN);
        const float bd = bsh[d];
        t0 += xv0 * bd;
        t1 += xv1 * bd;
    }
    partA[tid] = t0;
    partB[tid] = t1;
    __syncthreads();
    if (tid < 32) {
        floatx4 s = partA[tid];
        #pragma unroll
        for (int k = 1; k < 8; ++k) s += partA[k * 32 + tid];
        partA[tid] = s;
    } else if (tid < 64) {
        floatx4 s = partB[tid - 32];
        #pragma unroll
        for (int k = 1; k < 8; ++k) s += partB[k * 32 + (tid - 32)];
        partB[tid - 32] = s;
    }
    __syncthreads();
    t0 = partA[lane];
    t1 = partB[lane];

    // nontemporal: out is write-once, keep x resident in L3 instead
    #pragma unroll
    for (int d = g; d < D; d += 8) {
        const float sd = ssh[d];
        floatx4 o0 = t0 * sd;
        floatx4 o1 = t1 * sd;
        __builtin_nontemporal_store(o0, (floatx4*)(out + base0 + (size_t)d * NN));
        __builtin_nontemporal_store(o1, (floatx4*)(out + base1 + (size_t)d * NN));
    }
}

extern "C" void kernel_launch(void* const* d_in, const int* in_sizes, int n_in,
                              void* d_out, int out_size, void* d_ws, size_t ws_size,
                              hipStream_t stream)
{
    (void)in_sizes; (void)n_in; (void)out_size; (void)ws_size;
    const float* x     = (const float*)d_in[0];
    const float* bases = (const float*)d_in[1];
    float* out = (float*)d_out;

    // Scratch layout inside d_out (fully overwritten by out_kernel at the end):
    //   P: partial Gram tiles, 4*162*25600 floats = 66.4 MB at offset 0
    //   G: reduced Gram, 102,400 floats at float-offset 50,000,000 (200 MB; 16B-aligned)
    // d_out total = 4*16*160*72*72 = 53,084,160 floats -> both fit, no overlap.
    float* P    = (float*)d_out;
    float* G    = (float*)d_out + (size_t)50000000;
    float* bvec = (float*)d_ws;          // 4*160 floats
    float* svec = bvec + B * D;          // 4*160 floats

    gram_kernel<<<dim3(GRAM_BLOCKS, B), 256, 0, stream>>>(x, P);
    reduce_kernel<<<dim3(25, B), 256, 0, stream>>>(P, G);
    iter_kernel<<<dim3(B), 256, 0, stream>>>(bases, G, bvec, svec);
    out_kernel<<<dim3(NN / 256, B), 256, 0, stream>>>(x, bvec, svec, out);
}

// Round 2
// 440.277 us; speedup vs baseline: 1.0249x; 1.0149x over previous
//
#include <hip/hip_runtime.h>
#include <hip/hip_bf16.h>

#define EPS 1e-6f

constexpr int D  = 160;     // "D" axis (T//S)
constexpr int NN = 82944;   // C*H*W
constexpr int B  = 4;       // batches

typedef __bf16 bf16x8 __attribute__((ext_vector_type(8)));
typedef __bf16 bf16x4 __attribute__((ext_vector_type(4)));
typedef float  floatx4 __attribute__((ext_vector_type(4)));

// ---------------- Kernel A: partial Gram P[blk] = X_slab X_slab^T (bf16 MFMA) ----
// Two-stage split-K, private partial tiles (no atomics).
// This round: (1) double-buffered LDS -> ONE barrier per slab instead of two;
// (2) epilogue stores each wave's acc[i][j] as contiguous floatx4 per lane
//     (fully coalesced 1KB/wave NT stores) in a PERMUTED layout -- legal since
//     reduce_kernel sums element-wise and un-permutes when writing G.
constexpr int BK = 64;            // columns per LDS slab
constexpr int BKP = BK + 8;       // 144B row stride -> worst 2-way LDS aliasing (free)
constexpr int SLABS = 8;          // slabs per block
constexpr int COLS_PER_BLOCK = BK * SLABS;          // 512
constexpr int GRAM_BLOCKS = NN / COLS_PER_BLOCK;    // 162 (x4 batches = 648 blocks)

__global__ __launch_bounds__(256, 2)
void gram_kernel(const float* __restrict__ x, float* __restrict__ P)
{
    __shared__ __align__(16) __bf16 xs[2][D * BKP];   // 2 x 23.04 KB

    const int tid = threadIdx.x;
    const int batch = blockIdx.y;
    const int w  = tid >> 6;        // wave 0..3
    const int l  = tid & 63;
    const int lr = l & 15;          // row/col within 16-tile
    const int lq = l >> 4;          // quad 0..3
    const int itile0 = (w & 1) * 5; // wave's 5 row-tiles
    const int jtile0 = (w >> 1) * 5;// wave's 5 col-tiles
    const int srow = tid >> 4;      // staging: 16 lanes x 4 cols -> 64 cols/row
    const int scol = (tid & 15) * 4;

    const float* xb = x + (size_t)batch * D * NN + (size_t)blockIdx.x * COLS_PER_BLOCK;
    const float* pbase = xb + (size_t)srow * NN + scol;

    floatx4 acc[5][5] = {};
    float4 pf[10];

    // prologue: prefetch slab 0 into registers
    #pragma unroll
    for (int p = 0; p < 10; ++p)
        pf[p] = *(const float4*)(pbase + (size_t)p * 16 * NN);

    for (int s = 0; s < SLABS; ++s) {
        __bf16* buf = xs[s & 1];
        // store phase: convert prefetched fp32 -> bf16 LDS (other buffer than the
        // one iteration s-1 computes on -> no barrier needed before the stores;
        // the single barrier in iteration s-1 already separated us from the last
        // readers of this buffer at iteration s-2).
        #pragma unroll
        for (int p = 0; p < 10; ++p) {
            bf16x4 h = { (__bf16)pf[p].x, (__bf16)pf[p].y, (__bf16)pf[p].z, (__bf16)pf[p].w };
            *(bf16x4*)&buf[(srow + p * 16) * BKP + scol] = h;
        }
        // issue next slab's loads NOW -- they fly across the barrier + MFMA phase
        if (s + 1 < SLABS) {
            const float* pn = pbase + (s + 1) * BK;
            #pragma unroll
            for (int p = 0; p < 10; ++p)
                pf[p] = *(const float4*)(pn + (size_t)p * 16 * NN);
        }
        __syncthreads();   // our slab is fully staged -> compute may read it
        // compute phase: 2 k-chunks x 25 MFMA
        #pragma unroll
        for (int k = 0; k < BK / 32; ++k) {
            bf16x8 fa[5], fb[5];
            #pragma unroll
            for (int i = 0; i < 5; ++i) {
                fa[i] = *(const bf16x8*)&buf[((itile0 + i) * 16 + lr) * BKP + k * 32 + lq * 8];
                fb[i] = *(const bf16x8*)&buf[((jtile0 + i) * 16 + lr) * BKP + k * 32 + lq * 8];
            }
            #pragma unroll
            for (int i = 0; i < 5; ++i)
                #pragma unroll
                for (int j = 0; j < 5; ++j)
                    acc[i][j] = __builtin_amdgcn_mfma_f32_16x16x32_bf16(fa[i], fb[j], acc[i][j], 0, 0, 0);
        }
    }

    // epilogue: permuted coalesced layout. flat = w*6400 + (i*5+j)*256 + l*4 + r.
    // Each (i,j) fragment -> one contiguous 1KB NT store per wave.
    float* Pb = P + ((size_t)batch * GRAM_BLOCKS + blockIdx.x) * (size_t)(D * D)
                  + w * 6400 + l * 4;
    #pragma unroll
    for (int i = 0; i < 5; ++i)
        #pragma unroll
        for (int j = 0; j < 5; ++j)
            __builtin_nontemporal_store(acc[i][j], (floatx4*)(Pb + (i * 5 + j) * 256));
}

// ---------------- Kernel A2: G[b] = sum_k P[b][k] (162-way split-K reduce) -------
// grid (25, 4): 256 threads x float4 = 1024 floats/block. Reads are contiguous
// float4s in the permuted layout; the un-permute happens on the tiny G write
// (100 KB/batch scattered scalars -- negligible vs the 66 MB coalesced read).
__global__ __launch_bounds__(256)
void reduce_kernel(const float* __restrict__ P, float* __restrict__ G)
{
    const int batch = blockIdx.y;
    const int f4 = (blockIdx.x * 256 + threadIdx.x) * 4;
    const float* p = P + (size_t)batch * GRAM_BLOCKS * D * D + f4;
    floatx4 s = {0.f, 0.f, 0.f, 0.f};
    #pragma unroll 9     // 162 = 9*18 -> 9 loads (144B) in flight per thread
    for (int k = 0; k < GRAM_BLOCKS; ++k)
        s += __builtin_nontemporal_load((const floatx4*)(p + (size_t)k * D * D));

    // un-permute: flat = w*6400 + t*256 + l*4 + r, t = i*5+j
    const int w   = f4 / 6400;
    const int rem = f4 % 6400;
    const int t   = rem / 256;
    const int q   = rem % 256;
    const int i   = t / 5;
    const int j   = t % 5;
    const int l   = q >> 2;
    const int d1b = (w & 1) * 80 + i * 16 + (l >> 4) * 4;
    const int d2  = (w >> 1) * 80 + j * 16 + (l & 15);
    float* Gb = G + (size_t)batch * D * D;
    #pragma unroll
    for (int r = 0; r < 4; ++r)
        Gb[(size_t)(d1b + r) * D + d2] = s[r];
}

// ---------------- Kernel B: 4-step multiplicative update on G ----------------
__device__ __forceinline__ float block_reduce_bcast(float v, float* red)
{
    #pragma unroll
    for (int off = 32; off > 0; off >>= 1)
        v += __shfl_xor(v, off, 64);
    const int w = threadIdx.x >> 6;
    if ((threadIdx.x & 63) == 0) red[w] = v;
    __syncthreads();
    float s = red[0] + red[1] + red[2] + red[3];
    __syncthreads();
    return s;
}

__global__ __launch_bounds__(256)
void iter_kernel(const float* __restrict__ bases, const float* __restrict__ G,
                 float* __restrict__ bvec, float* __restrict__ svec)
{
    __shared__ float bs[D];
    __shared__ float red[4];
    const int batch = blockIdx.x;
    const int tid = threadIdx.x;
    const float* Gb = G + (size_t)batch * D * D;

    if (tid < D) bs[tid] = bases[batch * D + tid];
    __syncthreads();

    for (int step = 0; step < 4; ++step) {
        float v = (tid < D) ? bs[tid] * bs[tid] : 0.0f;
        const float btb = block_reduce_bcast(v, red);
        const float gamma = btb + EPS;           // exact at step 0 (coef==1); ~1e-6 rel after

        float m = 0.0f;
        if (tid < D) {
            const float* row = Gb + (size_t)tid * D;
            #pragma unroll 8
            for (int j = 0; j < D; j += 4) {
                float4 g4 = *(const float4*)(row + j);
                m += g4.x * bs[j] + g4.y * bs[j + 1] + g4.z * bs[j + 2] + g4.w * bs[j + 3];
            }
        }
        float bm = (tid < D) ? bs[tid] * m : 0.0f;
        const float beta = block_reduce_bcast(bm, red);   // b^T G b
        const float ctc = beta / (gamma * gamma);

        __syncthreads();
        if (tid < D) {
            const float bd = bs[tid];
            bs[tid] = bd * (m / gamma) / (bd * ctc + EPS);  // exact EPS in bases update
        }
        __syncthreads();
    }

    float v = (tid < D) ? bs[tid] * bs[tid] : 0.0f;
    const float btb = block_reduce_bcast(v, red);
    const float inv = 1.0f / (btb + EPS);
    if (tid < D) {
        bvec[batch * D + tid] = bs[tid];
        svec[batch * D + tid] = bs[tid] * inv;
    }
}

// ---------------- Kernel C: t = x^T b4 (fp32), out = (b4/btb4) t^T ----------------
// 256 cols/block: 40 independent loads in flight per thread.
__global__ __launch_bounds__(256)
void out_kernel(const float* __restrict__ x, const float* __restrict__ bvec,
                const float* __restrict__ svec, float* __restrict__ out)
{
    __shared__ float bsh[D], ssh[D];
    __shared__ floatx4 partA[256];
    __shared__ floatx4 partB[256];

    const int tid = threadIdx.x;
    const int batch = blockIdx.y;
    const int g = tid >> 5;          // d-group 0..7
    const int lane = tid & 31;
    const size_t base0 = (size_t)batch * D * NN + (size_t)blockIdx.x * 256 + lane * 4;
    const size_t base1 = base0 + 128;

    if (tid < D) { bsh[tid] = bvec[batch * D + tid]; ssh[tid] = svec[batch * D + tid]; }
    __syncthreads();

    floatx4 t0 = {0.f, 0.f, 0.f, 0.f};
    floatx4 t1 = {0.f, 0.f, 0.f, 0.f};
    #pragma unroll
    for (int d = g; d < D; d += 8) {
        floatx4 xv0 = *(const floatx4*)(x + base0 + (size_t)d * NN);
        floatx4 xv1 = *(const floatx4*)(x + base1 + (size_t)d * NN);
        const float bd = bsh[d];
        t0 += xv0 * bd;
        t1 += xv1 * bd;
    }
    partA[tid] = t0;
    partB[tid] = t1;
    __syncthreads();
    if (tid < 32) {
        floatx4 s = partA[tid];
        #pragma unroll
        for (int k = 1; k < 8; ++k) s += partA[k * 32 + tid];
        partA[tid] = s;
    } else if (tid < 64) {
        floatx4 s = partB[tid - 32];
        #pragma unroll
        for (int k = 1; k < 8; ++k) s += partB[k * 32 + (tid - 32)];
        partB[tid - 32] = s;
    }
    __syncthreads();
    t0 = partA[lane];
    t1 = partB[lane];

    // nontemporal: out is write-once, keep x resident in L3 instead
    #pragma unroll
    for (int d = g; d < D; d += 8) {
        const float sd = ssh[d];
        floatx4 o0 = t0 * sd;
        floatx4 o1 = t1 * sd;
        __builtin_nontemporal_store(o0, (floatx4*)(out + base0 + (size_t)d * NN));
        __builtin_nontemporal_store(o1, (floatx4*)(out + base1 + (size_t)d * NN));
    }
}

extern "C" void kernel_launch(void* const* d_in, const int* in_sizes, int n_in,
                              void* d_out, int out_size, void* d_ws, size_t ws_size,
                              hipStream_t stream)
{
    (void)in_sizes; (void)n_in; (void)out_size; (void)ws_size;
    const float* x     = (const float*)d_in[0];
    const float* bases = (const float*)d_in[1];
    float* out = (float*)d_out;

    // Scratch layout inside d_out (fully overwritten by out_kernel at the end):
    //   P: partial Gram tiles, 4*162*25600 floats = 66.4 MB at offset 0
    //   G: reduced Gram, 102,400 floats at float-offset 50,000,000 (200 MB; 16B-aligned)
    // d_out total = 4*16*160*72*72 = 53,084,160 floats -> both fit, no overlap.
    float* P    = (float*)d_out;
    float* G    = (float*)d_out + (size_t)50000000;
    float* bvec = (float*)d_ws;          // 4*160 floats
    float* svec = bvec + B * D;          // 4*160 floats

    gram_kernel<<<dim3(GRAM_BLOCKS, B), 256, 0, stream>>>(x, P);
    reduce_kernel<<<dim3(25, B), 256, 0, stream>>>(P, G);
    iter_kernel<<<dim3(B), 256, 0, stream>>>(bases, G, bvec, svec);
    out_kernel<<<dim3(NN / 256, B), 256, 0, stream>>>(x, bvec, svec, out);
}

// Round 3
// 432.370 us; speedup vs baseline: 1.0437x; 1.0183x over previous
//
#include <hip/hip_runtime.h>
#include <hip/hip_bf16.h>

#define EPS 1e-6f

constexpr int D  = 160;     // "D" axis (T//S)
constexpr int NN = 82944;   // C*H*W
constexpr int B  = 4;       // batches

typedef __bf16 bf16x8 __attribute__((ext_vector_type(8)));
typedef __bf16 bf16x4 __attribute__((ext_vector_type(4)));
typedef float  floatx4 __attribute__((ext_vector_type(4)));

// ---------------- Kernel A: partial Gram P[blk] = X_slab X_slab^T (bf16 MFMA) ----
// Pipelined split-K Gram. Key change this round: raw s_barrier + explicit
// lgkmcnt(0) instead of __syncthreads() -- __syncthreads() makes the compiler
// emit s_waitcnt vmcnt(0) which DRAINS the next-slab prefetch at every barrier
// (the m97-ceiling stall). With counted vmcnt the 10 next-slab loads stay in
// flight across the barrier and HBM latency hides under the MFMA phase.
// pfA/pfB are statically indexed (2x hand-unrolled slab loop) so they stay in
// registers (runtime-indexed ext_vector arrays go to scratch).
constexpr int BK = 64;            // columns per LDS slab
constexpr int BKP = BK + 8;       // 144B row stride -> worst 2-way LDS aliasing (free)
constexpr int SLABS = 16;         // slabs per block
constexpr int COLS_PER_BLOCK = BK * SLABS;          // 1024
constexpr int GRAM_BLOCKS = NN / COLS_PER_BLOCK;    // 81 (x4 batches = 324 blocks)

__global__ __launch_bounds__(256, 2)
void gram_kernel(const float* __restrict__ x, float* __restrict__ P)
{
    __shared__ __align__(16) __bf16 xs[2][D * BKP];   // 2 x 23.04 KB

    const int tid = threadIdx.x;
    const int batch = blockIdx.y;
    const int w  = tid >> 6;        // wave 0..3
    const int l  = tid & 63;
    const int lr = l & 15;          // row/col within 16-tile
    const int lq = l >> 4;          // quad 0..3
    const int itile0 = (w & 1) * 5; // wave's 5 row-tiles
    const int jtile0 = (w >> 1) * 5;// wave's 5 col-tiles
    const int srow = tid >> 4;      // staging: 16 lanes x 4 cols -> 64 cols/row
    const int scol = (tid & 15) * 4;

    const float* xb = x + (size_t)batch * D * NN + (size_t)blockIdx.x * COLS_PER_BLOCK;
    const float* pbase = xb + (size_t)srow * NN + scol;

    floatx4 acc[5][5] = {};
    float4 pfA[10], pfB[10];

    // prologue: prefetch slab 0
    #pragma unroll
    for (int p = 0; p < 10; ++p)
        pfA[p] = *(const float4*)(pbase + (size_t)p * 16 * NN);

    #define STORE_SLAB(PF, BUF)                                                     \
        _Pragma("unroll")                                                           \
        for (int p = 0; p < 10; ++p) {                                              \
            bf16x4 h = { (__bf16)PF[p].x, (__bf16)PF[p].y,                          \
                         (__bf16)PF[p].z, (__bf16)PF[p].w };                        \
            *(bf16x4*)&BUF[(srow + p * 16) * BKP + scol] = h;                       \
        }

    #define LOAD_SLAB(PF, SIDX)                                                     \
        {                                                                           \
            const float* pn = pbase + (size_t)(SIDX) * BK;                          \
            _Pragma("unroll")                                                       \
            for (int p = 0; p < 10; ++p)                                            \
                PF[p] = *(const float4*)(pn + (size_t)p * 16 * NN);                 \
        }

    #define COMPUTE_SLAB(BUF)                                                       \
        _Pragma("unroll")                                                           \
        for (int k = 0; k < BK / 32; ++k) {                                         \
            bf16x8 fa[5], fb[5];                                                    \
            _Pragma("unroll")                                                       \
            for (int i = 0; i < 5; ++i) {                                           \
                fa[i] = *(const bf16x8*)&BUF[((itile0 + i) * 16 + lr) * BKP + k * 32 + lq * 8]; \
                fb[i] = *(const bf16x8*)&BUF[((jtile0 + i) * 16 + lr) * BKP + k * 32 + lq * 8]; \
            }                                                                       \
            _Pragma("unroll")                                                       \
            for (int i = 0; i < 5; ++i)                                             \
                _Pragma("unroll")                                                   \
                for (int j = 0; j < 5; ++j)                                         \
                    acc[i][j] = __builtin_amdgcn_mfma_f32_16x16x32_bf16(fa[i], fb[j], acc[i][j], 0, 0, 0); \
        }

    for (int s = 0; s < SLABS; s += 2) {
        // ---- even slab s: data in pfA, stage into xs[0] ----
        LOAD_SLAB(pfB, s + 1);                       // next slab's loads fly
        STORE_SLAB(pfA, xs[0]);                      // compiler: counted vmcnt for pfA only
        asm volatile("s_waitcnt lgkmcnt(0)" ::: "memory");  // ds_writes visible
        __builtin_amdgcn_s_barrier();                // raw barrier: NO vmcnt drain
        COMPUTE_SLAB(xs[0]);                         // pfB loads land during this

        // ---- odd slab s+1: data in pfB, stage into xs[1] ----
        if (s + 2 < SLABS)
            LOAD_SLAB(pfA, s + 2);
        STORE_SLAB(pfB, xs[1]);
        asm volatile("s_waitcnt lgkmcnt(0)" ::: "memory");
        __builtin_amdgcn_s_barrier();
        COMPUTE_SLAB(xs[1]);
    }
    #undef STORE_SLAB
    #undef LOAD_SLAB
    #undef COMPUTE_SLAB

    // epilogue: permuted coalesced layout. flat = w*6400 + (i*5+j)*256 + l*4 + r.
    // Each (i,j) fragment -> one contiguous 1KB NT store per wave.
    float* Pb = P + ((size_t)batch * GRAM_BLOCKS + blockIdx.x) * (size_t)(D * D)
                  + w * 6400 + l * 4;
    #pragma unroll
    for (int i = 0; i < 5; ++i)
        #pragma unroll
        for (int j = 0; j < 5; ++j)
            __builtin_nontemporal_store(acc[i][j], (floatx4*)(Pb + (i * 5 + j) * 256));
}

// ---------------- Kernel A2: G[b] = sum_k P[b][k] (81-way split-K reduce) --------
// grid (25, 4): 256 threads x float4 = 1024 floats/block. Reads are contiguous
// float4s in the permuted layout; the un-permute happens on the tiny G write
// (100 KB/batch scattered scalars -- negligible vs the 33 MB coalesced read).
__global__ __launch_bounds__(256)
void reduce_kernel(const float* __restrict__ P, float* __restrict__ G)
{
    const int batch = blockIdx.y;
    const int f4 = (blockIdx.x * 256 + threadIdx.x) * 4;
    const float* p = P + (size_t)batch * GRAM_BLOCKS * D * D + f4;
    floatx4 s = {0.f, 0.f, 0.f, 0.f};
    #pragma unroll 9     // 81 = 9*9 -> 9 loads (144B) in flight per thread
    for (int k = 0; k < GRAM_BLOCKS; ++k)
        s += __builtin_nontemporal_load((const floatx4*)(p + (size_t)k * D * D));

    // un-permute: flat = w*6400 + t*256 + l*4 + r, t = i*5+j
    const int w   = f4 / 6400;
    const int rem = f4 % 6400;
    const int t   = rem / 256;
    const int q   = rem % 256;
    const int i   = t / 5;
    const int j   = t % 5;
    const int l   = q >> 2;
    const int d1b = (w & 1) * 80 + i * 16 + (l >> 4) * 4;
    const int d2  = (w >> 1) * 80 + j * 16 + (l & 15);
    float* Gb = G + (size_t)batch * D * D;
    #pragma unroll
    for (int r = 0; r < 4; ++r)
        Gb[(size_t)(d1b + r) * D + d2] = s[r];
}

// ---------------- Kernel B: 4-step multiplicative update on G ----------------
__device__ __forceinline__ float block_reduce_bcast(float v, float* red)
{
    #pragma unroll
    for (int off = 32; off > 0; off >>= 1)
        v += __shfl_xor(v, off, 64);
    const int w = threadIdx.x >> 6;
    if ((threadIdx.x & 63) == 0) red[w] = v;
    __syncthreads();
    float s = red[0] + red[1] + red[2] + red[3];
    __syncthreads();
    return s;
}

__global__ __launch_bounds__(256)
void iter_kernel(const float* __restrict__ bases, const float* __restrict__ G,
                 float* __restrict__ bvec, float* __restrict__ svec)
{
    __shared__ float bs[D];
    __shared__ float red[4];
    const int batch = blockIdx.x;
    const int tid = threadIdx.x;
    const float* Gb = G + (size_t)batch * D * D;

    if (tid < D) bs[tid] = bases[batch * D + tid];
    __syncthreads();

    for (int step = 0; step < 4; ++step) {
        float v = (tid < D) ? bs[tid] * bs[tid] : 0.0f;
        const float btb = block_reduce_bcast(v, red);
        const float gamma = btb + EPS;           // exact at step 0 (coef==1); ~1e-6 rel after

        float m = 0.0f;
        if (tid < D) {
            const float* row = Gb + (size_t)tid * D;
            #pragma unroll 8
            for (int j = 0; j < D; j += 4) {
                float4 g4 = *(const float4*)(row + j);
                m += g4.x * bs[j] + g4.y * bs[j + 1] + g4.z * bs[j + 2] + g4.w * bs[j + 3];
            }
        }
        float bm = (tid < D) ? bs[tid] * m : 0.0f;
        const float beta = block_reduce_bcast(bm, red);   // b^T G b
        const float ctc = beta / (gamma * gamma);

        __syncthreads();
        if (tid < D) {
            const float bd = bs[tid];
            bs[tid] = bd * (m / gamma) / (bd * ctc + EPS);  // exact EPS in bases update
        }
        __syncthreads();
    }

    float v = (tid < D) ? bs[tid] * bs[tid] : 0.0f;
    const float btb = block_reduce_bcast(v, red);
    const float inv = 1.0f / (btb + EPS);
    if (tid < D) {
        bvec[batch * D + tid] = bs[tid];
        svec[batch * D + tid] = bs[tid] * inv;
    }
}

// ---------------- Kernel C: t = x^T b4 (fp32), out = (b4/btb4) t^T ----------------
// 256 cols/block: 40 independent loads in flight per thread.
__global__ __launch_bounds__(256)
void out_kernel(const float* __restrict__ x, const float* __restrict__ bvec,
                const float* __restrict__ svec, float* __restrict__ out)
{
    __shared__ float bsh[D], ssh[D];
    __shared__ floatx4 partA[256];
    __shared__ floatx4 partB[256];

    const int tid = threadIdx.x;
    const int batch = blockIdx.y;
    const int g = tid >> 5;          // d-group 0..7
    const int lane = tid & 31;
    const size_t base0 = (size_t)batch * D * NN + (size_t)blockIdx.x * 256 + lane * 4;
    const size_t base1 = base0 + 128;

    if (tid < D) { bsh[tid] = bvec[batch * D + tid]; ssh[tid] = svec[batch * D + tid]; }
    __syncthreads();

    floatx4 t0 = {0.f, 0.f, 0.f, 0.f};
    floatx4 t1 = {0.f, 0.f, 0.f, 0.f};
    #pragma unroll
    for (int d = g; d < D; d += 8) {
        floatx4 xv0 = *(const floatx4*)(x + base0 + (size_t)d * NN);
        floatx4 xv1 = *(const floatx4*)(x + base1 + (size_t)d * NN);
        const float bd = bsh[d];
        t0 += xv0 * bd;
        t1 += xv1 * bd;
    }
    partA[tid] = t0;
    partB[tid] = t1;
    __syncthreads();
    if (tid < 32) {
        floatx4 s = partA[tid];
        #pragma unroll
        for (int k = 1; k < 8; ++k) s += partA[k * 32 + tid];
        partA[tid] = s;
    } else if (tid < 64) {
        floatx4 s = partB[tid - 32];
        #pragma unroll
        for (int k = 1; k < 8; ++k) s += partB[k * 32 + (tid - 32)];
        partB[tid - 32] = s;
    }
    __syncthreads();
    t0 = partA[lane];
    t1 = partB[lane];

    // nontemporal: out is write-once, keep x resident in L3 instead
    #pragma unroll
    for (int d = g; d < D; d += 8) {
        const float sd = ssh[d];
        floatx4 o0 = t0 * sd;
        floatx4 o1 = t1 * sd;
        __builtin_nontemporal_store(o0, (floatx4*)(out + base0 + (size_t)d * NN));
        __builtin_nontemporal_store(o1, (floatx4*)(out + base1 + (size_t)d * NN));
    }
}

extern "C" void kernel_launch(void* const* d_in, const int* in_sizes, int n_in,
                              void* d_out, int out_size, void* d_ws, size_t ws_size,
                              hipStream_t stream)
{
    (void)in_sizes; (void)n_in; (void)out_size; (void)ws_size;
    const float* x     = (const float*)d_in[0];
    const float* bases = (const float*)d_in[1];
    float* out = (float*)d_out;

    // Scratch layout inside d_out (fully overwritten by out_kernel at the end):
    //   P: partial Gram tiles, 4*81*25600 floats = 33.2 MB at offset 0
    //   G: reduced Gram, 102,400 floats at float-offset 50,000,000 (200 MB; 16B-aligned)
    // d_out total = 4*16*160*72*72 = 53,084,160 floats -> both fit, no overlap.
    float* P    = (float*)d_out;
    float* G    = (float*)d_out + (size_t)50000000;
    float* bvec = (float*)d_ws;          // 4*160 floats
    float* svec = bvec + B * D;          // 4*160 floats

    gram_kernel<<<dim3(GRAM_BLOCKS, B), 256, 0, stream>>>(x, P);
    reduce_kernel<<<dim3(25, B), 256, 0, stream>>>(P, G);
    iter_kernel<<<dim3(B), 256, 0, stream>>>(bases, G, bvec, svec);
    out_kernel<<<dim3(NN / 256, B), 256, 0, stream>>>(x, bvec, svec, out);
}